// Round 14
// baseline (2889.490 us; speedup 1.0000x reference)
//
#include <hip/hip_runtime.h>
#include <hip/hip_bf16.h>
#include <math.h>

#define DEMB 64
#define NPB 128            // nodes per bucket (c >> 7)
#define CHUNK 4096         // edges per binning workgroup
#define MAXBKT 1024
#define GSTR 68            // LDS accumulator row stride (floats) — breaks bank conflicts

typedef float v2f __attribute__((ext_vector_type(2)));
typedef short short8 __attribute__((ext_vector_type(8)));
typedef float f32x4 __attribute__((ext_vector_type(4)));

// ---------------- helpers ----------------

__device__ __forceinline__ float rdlane(float v, int k) {
    return __int_as_float(__builtin_amdgcn_readlane(__float_as_int(v), k));
}
__device__ __forceinline__ unsigned int f2bf(float f) {
    union { float f; unsigned int i; } c; c.f = f;
    unsigned int r = c.i + 0x7FFFu + ((c.i >> 16) & 1u);   // RNE
    return r >> 16;
}

// pack 64 lanes' y (feature=lane) into fp8 row; lanes 0..15 store one dword each
__device__ __forceinline__ void pack_store_fp8(float y, unsigned int* __restrict__ dst, int lane) {
    float y0 = __shfl(y, 4 * lane + 0);
    float y1 = __shfl(y, 4 * lane + 1);
    float y2 = __shfl(y, 4 * lane + 2);
    float y3 = __shfl(y, 4 * lane + 3);
    int u = __builtin_amdgcn_cvt_pk_fp8_f32(y0, y1, 0, false);
    u = __builtin_amdgcn_cvt_pk_fp8_f32(y2, y3, u, true);
    if (lane < 16) dst[lane] = (unsigned int)u;
}

// ---------------- preprocessing: zero-atomic exact-base bucket sort ----------------

// pass 1: per-chunk LDS histogram -> histM[wg][b] (raw counts)
__global__ __launch_bounds__(256) void histA_kernel(const int* __restrict__ ei,
                                                    int* __restrict__ histM,
                                                    int E, int NBKT) {
    __shared__ int lh[MAXBKT];
    int t = threadIdx.x;
    for (int b = t; b < NBKT; b += 256) lh[b] = 0;
    __syncthreads();
    int base = blockIdx.x * CHUNK;
    int end = base + CHUNK; if (end > E) end = E;
    for (int i = base + t; i < end; i += 256)
        atomicAdd(&lh[((unsigned int)ei[E + i]) >> 7], 1);
    __syncthreads();
    for (int b = t; b < NBKT; b += 256)
        histM[(size_t)blockIdx.x * NBKT + b] = lh[b];
}

// pass 2: column scan — for bucket b, exclusive-scan histM[:,b] over WGs; bktcnt[b]=total
__global__ __launch_bounds__(256) void scanM_kernel(int* __restrict__ histM,
                                                    int* __restrict__ bktcnt,
                                                    int NWG, int NBKT) {
    int b = blockIdx.x;
    int t = threadIdx.x, lane = t & 63, w = t >> 6;
    int w0 = 2 * t, w1 = 2 * t + 1;
    int v0 = (w0 < NWG) ? histM[(size_t)w0 * NBKT + b] : 0;
    int v1 = (w1 < NWG) ? histM[(size_t)w1 * NBKT + b] : 0;
    int s = v0 + v1;
    int sc = s;
    #pragma unroll
    for (int off = 1; off < 64; off <<= 1) {
        int u = __shfl_up(sc, off);
        if (lane >= off) sc += u;
    }
    __shared__ int wt[4];
    if (lane == 63) wt[w] = sc;
    __syncthreads();
    int woff = 0;
    for (int i = 0; i < w; i++) woff += wt[i];
    int ex = woff + sc - s;
    if (w0 < NWG) histM[(size_t)w0 * NBKT + b] = ex;
    if (w1 < NWG) histM[(size_t)w1 * NBKT + b] = ex + v0;
    if (t == 0) bktcnt[b] = wt[0] + wt[1] + wt[2] + wt[3];
}

// pass 3: single-block scan of bucket totals -> bktbase (exclusive + sentinel)
__global__ void scanB_kernel(const int* __restrict__ bktcnt, int* __restrict__ bktbase,
                             int NBKT) {
    __shared__ int sh[1024];
    int t = threadIdx.x;
    int mine = (t < NBKT) ? bktcnt[t] : 0;
    sh[t] = mine;
    __syncthreads();
    for (int off = 1; off < 1024; off <<= 1) {
        int v = (t >= off) ? sh[t - off] : 0;
        __syncthreads();
        sh[t] += v;
        __syncthreads();
    }
    if (t < NBKT) bktbase[t] = sh[t] - mine;
    if (t == 1023) bktbase[NBKT] = sh[1023];
}

// pass 4: single-pass scatter using exact bases. entry: x = (c&127)<<20 | r, y = bits(ew)
__global__ __launch_bounds__(256) void binA_kernel(const int* __restrict__ ei,
                                                   const float* __restrict__ ew,
                                                   const int* __restrict__ histM,
                                                   const int* __restrict__ bktbase,
                                                   int2* __restrict__ cells,
                                                   int E, int NBKT) {
    __shared__ int lbs[MAXBKT];
    __shared__ int lcur[MAXBKT];
    int t = threadIdx.x;
    for (int b = t; b < NBKT; b += 256) {
        lbs[b] = bktbase[b] + histM[(size_t)blockIdx.x * NBKT + b];
        lcur[b] = 0;
    }
    __syncthreads();
    int base = blockIdx.x * CHUNK;
    int end = base + CHUNK; if (end > E) end = E;
    for (int i = base + t; i < end; i += 256) {
        unsigned int c = (unsigned int)ei[E + i];
        unsigned int r = (unsigned int)ei[i];
        int wbits = __float_as_int(ew[i]);
        int bkt = c >> 7;
        int rel = atomicAdd(&lcur[bkt], 1);
        cells[lbs[bkt] + rel] = make_int2((int)(((c & 127u) << 20) | r), wbits);
    }
}

// pass 5: per-bucket weighted degree -> dis
__global__ __launch_bounds__(256) void degB_kernel(const int2* __restrict__ cells,
                                                   const int* __restrict__ bktbase,
                                                   float* __restrict__ dis, int N) {
    __shared__ float sdeg[NPB];
    int b = blockIdx.x;
    int t = threadIdx.x;
    if (t < NPB) sdeg[t] = 1.0f;           // self-loop weight
    __syncthreads();
    int lo = bktbase[b], hi = bktbase[b + 1];
    for (int i = lo + t; i < hi; i += 256) {
        int2 en = cells[i];
        atomicAdd(&sdeg[(((unsigned int)en.x) >> 20) & 127], __int_as_float(en.y));
    }
    __syncthreads();
    int node = (b << 7) + t;
    if (t < NPB && node < N) dis[node] = rsqrtf(sdeg[t]);
}

// ---------------- encoder: stores s = dis * h_enc as fp8 ----------------

__global__ __launch_bounds__(256, 4) void encoder_kernel(
    const float* __restrict__ x, const float* __restrict__ dis,
    const float* __restrict__ w1, const float* __restrict__ b1,
    const float* __restrict__ w2, const float* __restrict__ b2,
    unsigned int* __restrict__ hout4, int N) {
    int lane = threadIdx.x & 63;
    int wid = __builtin_amdgcn_readfirstlane((blockIdx.x * blockDim.x + threadIdx.x) >> 6);
    int n0 = wid * 4;
    if (n0 >= N) return;

    float w2col[DEMB];
    #pragma unroll
    for (int k = 0; k < DEMB; k++) w2col[k] = w2[k * DEMB + lane];
    float w1a = w1[lane], w1b = w1[DEMB + lane];
    float b1v = b1[lane], b2v = b2[lane];

    float xv = 0.0f;
    if (lane < 8 && n0 * 2 + lane < 2 * N) xv = x[n0 * 2 + lane];

    #pragma unroll
    for (int m = 0; m < 4; m++) {
        int node = n0 + m;
        if (node >= N) continue;
        float x0 = rdlane(xv, 2 * m);
        float x1 = rdlane(xv, 2 * m + 1);
        float t = fmaxf(0.0f, fmaf(x0, w1a, fmaf(x1, w1b, b1v)));
        float y = b2v;
        #pragma unroll
        for (int k = 0; k < DEMB; k++)
            y = fmaf(rdlane(t, k), w2col[k], y);
        pack_store_fp8(y * dis[node], hout4 + (size_t)node * 16, lane);
    }
}

// ------- FUSED layer: edge-streaming LDS scatter-add -> MFMA transform -------
// Block = one 128-node bucket, 512 threads (8 waves).
// Phase 1: stream cells[lo..hi): lane=(p=edge 0..15, q=feature-16-block 0..3);
//          one uint4 fp8 gather + 16 ds_add_f32 of w*val into Ga[ld][feat].
// Phase 2: A[m][k] = bf16((Ga[m][k] + self_m[k)) * dis_m); h'=relu(A·W+b)(*d) -> fp8.

__global__ __launch_bounds__(512, 6) void layer_kernel(
    const uint4* __restrict__ hin4, const int2* __restrict__ cells,
    const int* __restrict__ bktbase, const float* __restrict__ dis,
    const float* __restrict__ W, const float* __restrict__ bias,
    unsigned char* __restrict__ hout8, int N, int scaleOut) {
    __shared__ float Ga[NPB][GSTR];         // 34.8 KB
    int tid = threadIdx.x;
    int lane = tid & 63;
    int w = tid >> 6;                       // wave 0..7
    int b = blockIdx.x;
    int base = b << 7;

    float* gz = &Ga[0][0];
    for (int i = tid; i < NPB * GSTR; i += 512) gz[i] = 0.0f;
    __syncthreads();

    int lo = bktbase[b], hi = bktbase[b + 1];
    int p = (lane >> 2) & 15;               // edge slot 0..15
    int q = lane & 3;                       // feature 16-block
    for (int i = lo + w * 16; i < hi; i += 128) {
        int idx = i + p;
        int2 en = cells[(idx < hi) ? idx : (hi - 1)];
        float wt = (idx < hi) ? __int_as_float(en.y) : 0.0f;
        unsigned int ux = (unsigned int)en.x;
        int src = (int)(ux & 0xFFFFFu);
        int ld = (int)((ux >> 20) & 127u);
        uint4 u = hin4[(size_t)src * 4 + q];
        v2f c0 = __builtin_amdgcn_cvt_pk_f32_fp8((int)u.x, false);
        v2f c1 = __builtin_amdgcn_cvt_pk_f32_fp8((int)u.x, true);
        v2f c2 = __builtin_amdgcn_cvt_pk_f32_fp8((int)u.y, false);
        v2f c3 = __builtin_amdgcn_cvt_pk_f32_fp8((int)u.y, true);
        v2f c4 = __builtin_amdgcn_cvt_pk_f32_fp8((int)u.z, false);
        v2f c5 = __builtin_amdgcn_cvt_pk_f32_fp8((int)u.z, true);
        v2f c6 = __builtin_amdgcn_cvt_pk_f32_fp8((int)u.w, false);
        v2f c7 = __builtin_amdgcn_cvt_pk_f32_fp8((int)u.w, true);
        float* dst = &Ga[ld][q * 16];
        atomicAdd(&dst[0],  wt * c0.x); atomicAdd(&dst[1],  wt * c0.y);
        atomicAdd(&dst[2],  wt * c1.x); atomicAdd(&dst[3],  wt * c1.y);
        atomicAdd(&dst[4],  wt * c2.x); atomicAdd(&dst[5],  wt * c2.y);
        atomicAdd(&dst[6],  wt * c3.x); atomicAdd(&dst[7],  wt * c3.y);
        atomicAdd(&dst[8],  wt * c4.x); atomicAdd(&dst[9],  wt * c4.y);
        atomicAdd(&dst[10], wt * c5.x); atomicAdd(&dst[11], wt * c5.y);
        atomicAdd(&dst[12], wt * c6.x); atomicAdd(&dst[13], wt * c6.y);
        atomicAdd(&dst[14], wt * c7.x); atomicAdd(&dst[15], wt * c7.y);
    }
    __syncthreads();

    // phase 2: wave w transforms m-tile w (nodes base+w*16 .. +15)
    int col = lane & 15, quad = lane >> 4;

    short8 Bf[4][2];
    #pragma unroll
    for (int nt = 0; nt < 4; nt++)
        #pragma unroll
        for (int kt = 0; kt < 2; kt++)
            #pragma unroll
            for (int j = 0; j < 8; j++)
                Bf[nt][kt][j] = (short)f2bf(W[(kt * 32 + quad * 8 + j) * DEMB + nt * 16 + col]);
    float bv[4];
    #pragma unroll
    for (int nt = 0; nt < 4; nt++) bv[nt] = bias[nt * 16 + col];

    int mrow = base + w * 16 + col;
    int mc = (mrow < N) ? mrow : (N - 1);
    float dA = dis[mc];
    const uint2* hin2 = (const uint2*)hin4;
    uint2 sA = hin2[(size_t)mc * 8 + quad];       // self features quad*8..+7
    uint2 sB = hin2[(size_t)mc * 8 + 4 + quad];   // self features 32+quad*8..+7
    v2f sa0 = __builtin_amdgcn_cvt_pk_f32_fp8((int)sA.x, false);
    v2f sa1 = __builtin_amdgcn_cvt_pk_f32_fp8((int)sA.x, true);
    v2f sa2 = __builtin_amdgcn_cvt_pk_f32_fp8((int)sA.y, false);
    v2f sa3 = __builtin_amdgcn_cvt_pk_f32_fp8((int)sA.y, true);
    v2f sb0 = __builtin_amdgcn_cvt_pk_f32_fp8((int)sB.x, false);
    v2f sb1 = __builtin_amdgcn_cvt_pk_f32_fp8((int)sB.x, true);
    v2f sb2 = __builtin_amdgcn_cvt_pk_f32_fp8((int)sB.y, false);
    v2f sb3 = __builtin_amdgcn_cvt_pk_f32_fp8((int)sB.y, true);
    const float* gr = &Ga[w * 16 + col][0];
    short8 Af0, Af1;
    Af0[0] = (short)f2bf((gr[quad * 8 + 0] + sa0.x) * dA);
    Af0[1] = (short)f2bf((gr[quad * 8 + 1] + sa0.y) * dA);
    Af0[2] = (short)f2bf((gr[quad * 8 + 2] + sa1.x) * dA);
    Af0[3] = (short)f2bf((gr[quad * 8 + 3] + sa1.y) * dA);
    Af0[4] = (short)f2bf((gr[quad * 8 + 4] + sa2.x) * dA);
    Af0[5] = (short)f2bf((gr[quad * 8 + 5] + sa2.y) * dA);
    Af0[6] = (short)f2bf((gr[quad * 8 + 6] + sa3.x) * dA);
    Af0[7] = (short)f2bf((gr[quad * 8 + 7] + sa3.y) * dA);
    Af1[0] = (short)f2bf((gr[32 + quad * 8 + 0] + sb0.x) * dA);
    Af1[1] = (short)f2bf((gr[32 + quad * 8 + 1] + sb0.y) * dA);
    Af1[2] = (short)f2bf((gr[32 + quad * 8 + 2] + sb1.x) * dA);
    Af1[3] = (short)f2bf((gr[32 + quad * 8 + 3] + sb1.y) * dA);
    Af1[4] = (short)f2bf((gr[32 + quad * 8 + 4] + sb2.x) * dA);
    Af1[5] = (short)f2bf((gr[32 + quad * 8 + 5] + sb2.y) * dA);
    Af1[6] = (short)f2bf((gr[32 + quad * 8 + 6] + sb3.x) * dA);
    Af1[7] = (short)f2bf((gr[32 + quad * 8 + 7] + sb3.y) * dA);

    f32x4 acc[4];
    #pragma unroll
    for (int nt = 0; nt < 4; nt++) {
        f32x4 z = {0.0f, 0.0f, 0.0f, 0.0f};
        z = __builtin_amdgcn_mfma_f32_16x16x32_bf16(Af0, Bf[nt][0], z, 0, 0, 0);
        z = __builtin_amdgcn_mfma_f32_16x16x32_bf16(Af1, Bf[nt][1], z, 0, 0, 0);
        acc[nt] = z;
    }

    #pragma unroll
    for (int reg = 0; reg < 4; reg++) {
        int node = base + w * 16 + quad * 4 + reg;
        if (node >= N) continue;
        float d = dis[node];
        float os = scaleOut ? d : 1.0f;
        #pragma unroll
        for (int nt = 0; nt < 4; nt++) {
            float y = fmaxf(acc[nt][reg] + bv[nt], 0.0f) * os;
            int u = __builtin_amdgcn_cvt_pk_fp8_f32(y, y, 0, false);
            hout8[(size_t)node * DEMB + nt * 16 + col] = (unsigned char)(u & 0xff);
        }
    }
}

// ---------------- decoder + softmax + residual ----------------

__global__ __launch_bounds__(256, 4) void decoder_kernel(
    const unsigned char* __restrict__ h8, const float* __restrict__ x,
    const float* __restrict__ dw1, const float* __restrict__ db1,
    const float* __restrict__ dw2, const float* __restrict__ db2,
    float* __restrict__ out, int N) {
    int lane = threadIdx.x & 63;
    int wid = __builtin_amdgcn_readfirstlane((blockIdx.x * blockDim.x + threadIdx.x) >> 6);
    int n0 = wid * 4;
    if (n0 >= N) return;

    float w1col[DEMB];
    #pragma unroll
    for (int k = 0; k < DEMB; k++) w1col[k] = dw1[k * DEMB + lane];
    float db1v = db1[lane];
    float w20 = dw2[lane * 2], w21 = dw2[lane * 2 + 1];
    float db20 = db2[0], db21 = db2[1];

    float xv = 0.0f;
    if (lane < 8 && n0 * 2 + lane < 2 * N) xv = x[n0 * 2 + lane];

    float myout = 0.0f;
    #pragma unroll
    for (int m = 0; m < 4; m++) {
        int node = n0 + m;
        if (node >= N) continue;
        float hv = __builtin_amdgcn_cvt_f32_fp8((int)h8[(size_t)node * 64 + lane], 0);
        float y = db1v;
        #pragma unroll
        for (int k = 0; k < DEMB; k++)
            y = fmaf(rdlane(hv, k), w1col[k], y);
        float d1 = fmaxf(y, 0.0f);
        float p0 = d1 * w20, p1 = d1 * w21;
        #pragma unroll
        for (int off = 32; off > 0; off >>= 1) {
            p0 += __shfl_xor(p0, off);
            p1 += __shfl_xor(p1, off);
        }
        float o0 = p0 + db20, o1 = p1 + db21;
        float mm = fmaxf(o0, o1);
        float e0 = __expf(o0 - mm), e1 = __expf(o1 - mm);
        float inv = 1.0f / (e0 + e1);
        float r0 = e0 * inv + 2.0f * rdlane(xv, 2 * m);   // wc = [2, 0]
        float r1 = e1 * inv;
        if (lane == 2 * m) myout = r0;
        if (lane == 2 * m + 1) myout = r1;
    }
    if (lane < 8 && n0 * 2 + lane < 2 * N)
        out[n0 * 2 + lane] = myout;
}

// ---------------- launch ----------------

extern "C" void kernel_launch(void* const* d_in, const int* in_sizes, int n_in,
                              void* d_out, int out_size, void* d_ws, size_t ws_size,
                              hipStream_t stream) {
    const float* x      = (const float*)d_in[0];
    const int*   ei     = (const int*)d_in[1];
    const float* ew     = (const float*)d_in[2];
    const float* enc_w1 = (const float*)d_in[3];
    const float* enc_b1 = (const float*)d_in[4];
    const float* enc_w2 = (const float*)d_in[5];
    const float* enc_b2 = (const float*)d_in[6];
    const float* gcn_w  = (const float*)d_in[7];
    const float* gcn_b  = (const float*)d_in[8];
    const float* dec_w1 = (const float*)d_in[9];
    const float* dec_b1 = (const float*)d_in[10];
    const float* dec_w2 = (const float*)d_in[11];
    const float* dec_b2 = (const float*)d_in[12];
    float* out = (float*)d_out;

    const int N = in_sizes[0] / 2;
    const int E = in_sizes[2];
    const int L = in_sizes[7] / (DEMB * DEMB);
    const int NBKT = (N + NPB - 1) / NPB;
    const int NWG = (E + CHUNK - 1) / CHUNK;

    // workspace layout (256B aligned); h rows 64 B fp8
    char* ws = (char*)d_ws;
    size_t o = 0;
    auto alignup = [](size_t v) { return (v + 255) & ~(size_t)255; };
    unsigned int* hA = (unsigned int*)(ws + o); o = alignup(o + (size_t)N * DEMB);
    unsigned int* hB = (unsigned int*)(ws + o); o = alignup(o + (size_t)N * DEMB);
    float* dis     = (float*)(ws + o); o = alignup(o + (size_t)N * 4);
    int*   histM   = (int*)(ws + o);   o = alignup(o + (size_t)NWG * NBKT * 4);
    int*   bktcnt  = (int*)(ws + o);   o = alignup(o + (size_t)MAXBKT * 4);
    int*   bktbase = (int*)(ws + o);   o = alignup(o + (size_t)(MAXBKT + 1) * 4);
    int2*  cells   = (int2*)(ws + o);  o = alignup(o + (size_t)E * 8);

    const int TB = 256;
    dim3 blk(TB);
    dim3 gWave4((N * 16 + TB - 1) / TB);          // wave per 4 nodes

    histA_kernel<<<NWG, blk, 0, stream>>>(ei, histM, E, NBKT);
    scanM_kernel<<<NBKT, blk, 0, stream>>>(histM, bktcnt, NWG, NBKT);
    scanB_kernel<<<1, 1024, 0, stream>>>(bktcnt, bktbase, NBKT);
    binA_kernel<<<NWG, blk, 0, stream>>>(ei, ew, histM, bktbase, cells, E, NBKT);
    degB_kernel<<<NBKT, blk, 0, stream>>>(cells, bktbase, dis, N);

    encoder_kernel<<<gWave4, blk, 0, stream>>>(x, dis, enc_w1, enc_b1, enc_w2, enc_b2, hA, N);

    unsigned int* hin = hA;
    unsigned int* hout = hB;
    for (int l = 0; l < L; l++) {
        layer_kernel<<<NBKT, dim3(512), 0, stream>>>(
            (const uint4*)hin, cells, bktbase, dis,
            gcn_w + (size_t)l * DEMB * DEMB, gcn_b + (size_t)l * DEMB,
            (unsigned char*)hout, N, (l < L - 1) ? 1 : 0);
        unsigned int* t = hin; hin = hout; hout = t;
    }

    decoder_kernel<<<gWave4, blk, 0, stream>>>((const unsigned char*)hin, x,
                                               dec_w1, dec_b1, dec_w2, dec_b2, out, N);
}

// Round 15
// 382.862 us; speedup vs baseline: 7.5471x; 7.5471x over previous
//
#include <hip/hip_runtime.h>
#include <hip/hip_bf16.h>
#include <math.h>

#define DEMB 64
#define NPBKT 256          // nodes per coarse bucket (c >> 8)
#define CHUNK 4096         // edges per binning workgroup
#define MAXBKT 512
#define SENT_CAP 7168      // LDS staging entries in pass B (57 KB)

typedef float v2f __attribute__((ext_vector_type(2)));
typedef short short8 __attribute__((ext_vector_type(8)));
typedef float f32x4 __attribute__((ext_vector_type(4)));

// ---------------- helpers ----------------

__device__ __forceinline__ float rdlane(float v, int k) {
    return __int_as_float(__builtin_amdgcn_readlane(__float_as_int(v), k));
}
__device__ __forceinline__ unsigned int f2bf(float f) {
    union { float f; unsigned int i; } c; c.f = f;
    unsigned int r = c.i + 0x7FFFu + ((c.i >> 16) & 1u);   // RNE
    return r >> 16;
}

// pack 64 lanes' y (feature=lane) into fp8 row; lanes 0..15 store one dword each
__device__ __forceinline__ void pack_store_fp8(float y, unsigned int* __restrict__ dst, int lane) {
    float y0 = __shfl(y, 4 * lane + 0);
    float y1 = __shfl(y, 4 * lane + 1);
    float y2 = __shfl(y, 4 * lane + 2);
    float y3 = __shfl(y, 4 * lane + 3);
    int u = __builtin_amdgcn_cvt_pk_fp8_f32(y0, y1, 0, false);
    u = __builtin_amdgcn_cvt_pk_fp8_f32(y2, y3, u, true);
    if (lane < 16) dst[lane] = (unsigned int)u;
}

// ---------------- preprocessing: zero-atomic exact-base counting sort ----------------

__global__ __launch_bounds__(256) void histA_kernel(const int* __restrict__ ei,
                                                    int* __restrict__ histM,
                                                    int E, int NBKT) {
    __shared__ int lh[MAXBKT];
    int t = threadIdx.x;
    for (int b = t; b < MAXBKT; b += 256) lh[b] = 0;
    __syncthreads();
    int base = blockIdx.x * CHUNK;
    int end = base + CHUNK; if (end > E) end = E;
    for (int i = base + t; i < end; i += 256)
        atomicAdd(&lh[((unsigned int)ei[E + i]) >> 8], 1);
    __syncthreads();
    for (int b = t; b < NBKT; b += 256) {
        int c = lh[b];
        histM[(size_t)blockIdx.x * NBKT + b] = c ? ((c + 7) & ~7) : 0;
    }
}

__global__ __launch_bounds__(256) void scanM_kernel(int* __restrict__ histM,
                                                    int* __restrict__ bktcnt,
                                                    int NWG, int NBKT) {
    int b = blockIdx.x;
    int t = threadIdx.x, lane = t & 63, w = t >> 6;
    int w0 = 2 * t, w1 = 2 * t + 1;
    int v0 = (w0 < NWG) ? histM[(size_t)w0 * NBKT + b] : 0;
    int v1 = (w1 < NWG) ? histM[(size_t)w1 * NBKT + b] : 0;
    int s = v0 + v1;
    int sc = s;
    #pragma unroll
    for (int off = 1; off < 64; off <<= 1) {
        int u = __shfl_up(sc, off);
        if (lane >= off) sc += u;
    }
    __shared__ int wt[4];
    if (lane == 63) wt[w] = sc;
    __syncthreads();
    int woff = 0;
    for (int i = 0; i < w; i++) woff += wt[i];
    int ex = woff + sc - s;
    if (w0 < NWG) histM[(size_t)w0 * NBKT + b] = ex;
    if (w1 < NWG) histM[(size_t)w1 * NBKT + b] = ex + v0;
    if (t == 0) bktcnt[b] = wt[0] + wt[1] + wt[2] + wt[3];
}

__global__ void scanB_kernel(const int* __restrict__ bktcnt, int* __restrict__ bktbase,
                             int NBKT) {
    __shared__ int sh[512];
    int t = threadIdx.x;
    int mine = (t < NBKT) ? bktcnt[t] : 0;
    sh[t] = mine;
    __syncthreads();
    for (int off = 1; off < 512; off <<= 1) {
        int v = (t >= off) ? sh[t - off] : 0;
        __syncthreads();
        sh[t] += v;
        __syncthreads();
    }
    if (t < NBKT) bktbase[t] = sh[t] - mine;
    if (t == 511) bktbase[NBKT] = sh[511];
}

// entry: x = (c&255)<<20 | r  (valid x >= 0), sentinel pad x = -1
__global__ __launch_bounds__(256) void binA_kernel(const int* __restrict__ ei,
                                                   const float* __restrict__ ew,
                                                   const int* __restrict__ histM,
                                                   const int* __restrict__ bktbase,
                                                   int2* __restrict__ cells,
                                                   int E, int NBKT) {
    __shared__ int lh[MAXBKT];
    __shared__ int lbs[MAXBKT];
    __shared__ int lcur[MAXBKT];
    int t = threadIdx.x;
    for (int b = t; b < MAXBKT; b += 256) { lh[b] = 0; lcur[b] = 0; }
    __syncthreads();
    int base = blockIdx.x * CHUNK;
    int end = base + CHUNK; if (end > E) end = E;

    int cc[CHUNK / 256];
    int nloc = 0;
    for (int i = base + t; i < end; i += 256, nloc++) {
        int c = ei[E + i];
        cc[nloc] = c;
        atomicAdd(&lh[((unsigned int)c) >> 8], 1);
    }
    __syncthreads();
    for (int b = t; b < NBKT; b += 256)
        lbs[b] = bktbase[b] + histM[(size_t)blockIdx.x * NBKT + b];
    __syncthreads();
    int k = 0;
    for (int i = base + t; i < end; i += 256, k++) {
        unsigned int c = (unsigned int)cc[k];
        unsigned int r = (unsigned int)ei[i];
        int wbits = __float_as_int(ew[i]);
        int bkt = c >> 8;
        int rel = atomicAdd(&lcur[bkt], 1);
        cells[lbs[bkt] + rel] = make_int2((int)(((c & 255u) << 20) | r), wbits);
    }
    __syncthreads();
    for (int b = t; b < NBKT; b += 256) {
        int cnt = lh[b];
        if (cnt) {
            int pc = (cnt + 7) & ~7;
            for (int j = cnt; j < pc; j++)
                cells[lbs[b] + j] = make_int2(-1, 0);
        }
    }
}

// pass B: per bucket — count + weighted degree (skip sentinels), 8-quantum padded scan,
// write dis/rowse (padded ends), sort into LDS with (self,0) row pads, stream CSR out.
__global__ __launch_bounds__(256) void bucketB_kernel(
    const int2* __restrict__ cells, const int* __restrict__ bktbase,
    int2* __restrict__ csr, int2* __restrict__ rowse, float* __restrict__ dis, int N) {
    __shared__ int scnt[NPBKT];
    __shared__ float sdeg[NPBKT];
    __shared__ int sstart[NPBKT];
    __shared__ int sfill[NPBKT];
    __shared__ int ssc[NPBKT];
    __shared__ int2 sout[SENT_CAP];

    int b = blockIdx.x;
    int t = threadIdx.x;
    int nodebase = b << 8;
    int nNodes = N - nodebase; if (nNodes > NPBKT) nNodes = NPBKT;

    if (t < NPBKT) { scnt[t] = 0; sdeg[t] = 1.0f; sfill[t] = 0; }   // self-loop deg=1
    __syncthreads();

    int lo = bktbase[b], hi = bktbase[b + 1];
    int outbase = lo + b * (NPBKT * 7);     // room for row pads, disjoint per bucket

    for (int i = lo + t; i < hi; i += 256) {
        int2 en = cells[i];
        if (en.x >= 0) {
            unsigned int ld = ((unsigned int)en.x) >> 20;
            atomicAdd(&scnt[ld], 1);
            atomicAdd(&sdeg[ld], __int_as_float(en.y));
        }
    }
    __syncthreads();

    int cnt_t = scnt[t];
    int pc_t = (cnt_t + 7) & ~7;            // padded row length
    ssc[t] = pc_t;
    __syncthreads();
    for (int off = 1; off < NPBKT; off <<= 1) {
        int v = (t >= off) ? ssc[t - off] : 0;
        __syncthreads();
        ssc[t] += v;
        __syncthreads();
    }
    sstart[t] = ssc[t] - pc_t;
    __syncthreads();
    int ptotal = ssc[NPBKT - 1];

    if (t < nNodes) {
        int node = nodebase + t;
        dis[node] = rsqrtf(sdeg[t]);
        rowse[node] = make_int2(outbase + sstart[t], outbase + sstart[t] + pc_t);
    }

    if (ptotal <= SENT_CAP) {
        for (int i = lo + t; i < hi; i += 256) {
            int2 en = cells[i];
            if (en.x >= 0) {
                unsigned int ux = (unsigned int)en.x;
                unsigned int ld = ux >> 20;
                int pos = sstart[ld] + atomicAdd(&sfill[ld], 1);
                sout[pos] = make_int2((int)(ux & 0xFFFFFu), en.y);
            }
        }
        __syncthreads();
        if (t < nNodes) {
            for (int j = cnt_t; j < pc_t; j++)
                sout[sstart[t] + j] = make_int2(nodebase + t, 0);   // (self, w=0) pad
        }
        __syncthreads();
        for (int i = t; i < ptotal; i += 256)
            csr[outbase + i] = sout[i];
    } else {
        // pathological-skew fallback: direct global scatter
        for (int i = lo + t; i < hi; i += 256) {
            int2 en = cells[i];
            if (en.x >= 0) {
                unsigned int ux = (unsigned int)en.x;
                unsigned int ld = ux >> 20;
                int pos = atomicAdd(&sfill[ld], 1);
                csr[outbase + sstart[ld] + pos] = make_int2((int)(ux & 0xFFFFFu), en.y);
            }
        }
        __syncthreads();
        if (t < nNodes) {
            for (int j = cnt_t; j < pc_t; j++)
                csr[outbase + sstart[t] + j] = make_int2(nodebase + t, 0);
        }
    }
}

// ---------------- encoder: stores s = dis * h_enc as fp8 ----------------

__global__ __launch_bounds__(256, 4) void encoder_kernel(
    const float* __restrict__ x, const float* __restrict__ dis,
    const float* __restrict__ w1, const float* __restrict__ b1,
    const float* __restrict__ w2, const float* __restrict__ b2,
    unsigned int* __restrict__ hout4, int N) {
    int lane = threadIdx.x & 63;
    int wid = __builtin_amdgcn_readfirstlane((blockIdx.x * blockDim.x + threadIdx.x) >> 6);
    int n0 = wid * 4;
    if (n0 >= N) return;

    float w2col[DEMB];
    #pragma unroll
    for (int k = 0; k < DEMB; k++) w2col[k] = w2[k * DEMB + lane];
    float w1a = w1[lane], w1b = w1[DEMB + lane];
    float b1v = b1[lane], b2v = b2[lane];

    float xv = 0.0f;
    if (lane < 8 && n0 * 2 + lane < 2 * N) xv = x[n0 * 2 + lane];

    #pragma unroll
    for (int m = 0; m < 4; m++) {
        int node = n0 + m;
        if (node >= N) continue;
        float x0 = rdlane(xv, 2 * m);
        float x1 = rdlane(xv, 2 * m + 1);
        float t = fmaxf(0.0f, fmaf(x0, w1a, fmaf(x1, w1b, b1v)));
        float y = b2v;
        #pragma unroll
        for (int k = 0; k < DEMB; k++)
            y = fmaf(rdlane(t, k), w2col[k], y);
        pack_store_fp8(y * dis[node], hout4 + (size_t)node * 16, lane);
    }
}

// ------- aggregation: 2 nodes/wave, 8 slots, uint4 (16B) gathers on fp8 rows -------
// lane = m*32 + p*4 + q: m=node, p=edge slot 0..7, q=feature 16-block 0..3
// CSR rows are 8-quantum padded with (self, w=0) — no bounds checks in the slot loop.
// writes g = dis_c * (Σ ew*s_src + s_c) as bf16 row [64] (128 B)

__device__ __forceinline__ void agg_acc8(v2f* __restrict__ acc, uint4 u, float w) {
    v2f wv = {w, w};
    acc[0] += wv * __builtin_amdgcn_cvt_pk_f32_fp8((int)u.x, false);
    acc[1] += wv * __builtin_amdgcn_cvt_pk_f32_fp8((int)u.x, true);
    acc[2] += wv * __builtin_amdgcn_cvt_pk_f32_fp8((int)u.y, false);
    acc[3] += wv * __builtin_amdgcn_cvt_pk_f32_fp8((int)u.y, true);
    acc[4] += wv * __builtin_amdgcn_cvt_pk_f32_fp8((int)u.z, false);
    acc[5] += wv * __builtin_amdgcn_cvt_pk_f32_fp8((int)u.z, true);
    acc[6] += wv * __builtin_amdgcn_cvt_pk_f32_fp8((int)u.w, false);
    acc[7] += wv * __builtin_amdgcn_cvt_pk_f32_fp8((int)u.w, true);
}

__global__ __launch_bounds__(256, 8) void agg_kernel(
    const uint4* __restrict__ hin4, const int2* __restrict__ csr,
    const int2* __restrict__ rowse, const float* __restrict__ dis,
    uint4* __restrict__ Gout, int N) {
    int lane = threadIdx.x & 63;
    int wid = __builtin_amdgcn_readfirstlane((blockIdx.x * blockDim.x + threadIdx.x) >> 6);
    int n0 = wid * 2;
    if (n0 >= N) return;
    int m = lane >> 5;
    int p = (lane >> 2) & 7;
    int q = lane & 3;
    int node = n0 + m;
    bool valid = node < N;
    if (!valid) node = N - 1;

    uint4 su = hin4[(size_t)node * 4 + q];
    v2f acc[8];
    float sw = (p == 0) ? 1.0f : 0.0f;
    v2f swv = {sw, sw};
    acc[0] = swv * __builtin_amdgcn_cvt_pk_f32_fp8((int)su.x, false);
    acc[1] = swv * __builtin_amdgcn_cvt_pk_f32_fp8((int)su.x, true);
    acc[2] = swv * __builtin_amdgcn_cvt_pk_f32_fp8((int)su.y, false);
    acc[3] = swv * __builtin_amdgcn_cvt_pk_f32_fp8((int)su.y, true);
    acc[4] = swv * __builtin_amdgcn_cvt_pk_f32_fp8((int)su.z, false);
    acc[5] = swv * __builtin_amdgcn_cvt_pk_f32_fp8((int)su.z, true);
    acc[6] = swv * __builtin_amdgcn_cvt_pk_f32_fp8((int)su.w, false);
    acc[7] = swv * __builtin_amdgcn_cvt_pk_f32_fp8((int)su.w, true);

    int2 se = rowse[node];
    int s = se.x, e = se.y;                 // padded to multiple of 8
    for (int i = s; i < e; i += 16) {
        int2 eA = csr[i + p];               // broadcast over 4 q-lanes
        uint4 uA = hin4[(size_t)eA.x * 4 + q];
        if (i + 8 < e) {
            int2 eB = csr[i + 8 + p];
            uint4 uB = hin4[(size_t)eB.x * 4 + q];
            agg_acc8(acc, uA, __int_as_float(eA.y));
            agg_acc8(acc, uB, __int_as_float(eB.y));
        } else {
            agg_acc8(acc, uA, __int_as_float(eA.y));
        }
    }

    // reduce over p (lane bits 2..4): xor 4, 8, 16
    #pragma unroll
    for (int off = 4; off <= 16; off <<= 1) {
        #pragma unroll
        for (int k = 0; k < 8; k++) {
            acc[k].x += __shfl_xor(acc[k].x, off);
            acc[k].y += __shfl_xor(acc[k].y, off);
        }
    }

    float d = dis[node];
    if (p == 0 && valid) {
        uint4 g0, g1;
        g0.x = f2bf(acc[0].x * d) | (f2bf(acc[0].y * d) << 16);
        g0.y = f2bf(acc[1].x * d) | (f2bf(acc[1].y * d) << 16);
        g0.z = f2bf(acc[2].x * d) | (f2bf(acc[2].y * d) << 16);
        g0.w = f2bf(acc[3].x * d) | (f2bf(acc[3].y * d) << 16);
        g1.x = f2bf(acc[4].x * d) | (f2bf(acc[4].y * d) << 16);
        g1.y = f2bf(acc[5].x * d) | (f2bf(acc[5].y * d) << 16);
        g1.z = f2bf(acc[6].x * d) | (f2bf(acc[6].y * d) << 16);
        g1.w = f2bf(acc[7].x * d) | (f2bf(acc[7].y * d) << 16);
        Gout[(size_t)node * 8 + q * 2] = g0;        // features 16q..16q+7
        Gout[(size_t)node * 8 + q * 2 + 1] = g1;    // features 16q+8..16q+15
    }
}

// ------- transform: 16-node MFMA GEMM  h' = relu(G·W + b) (* d if scaleOut) -> fp8 -------

__global__ __launch_bounds__(256) void transform_kernel(
    const unsigned short* __restrict__ G, const float* __restrict__ W,
    const float* __restrict__ bias, const float* __restrict__ dis,
    unsigned char* __restrict__ hout8, int N, int scaleOut) {
    int lane = threadIdx.x & 63;
    int wv = (blockIdx.x * blockDim.x + threadIdx.x) >> 6;
    int base = wv * 16;
    if (base >= N) return;
    int col = lane & 15, quad = lane >> 4;

    short8 Bf[4][2];
    #pragma unroll
    for (int nt = 0; nt < 4; nt++)
        #pragma unroll
        for (int kt = 0; kt < 2; kt++)
            #pragma unroll
            for (int j = 0; j < 8; j++)
                Bf[nt][kt][j] = (short)f2bf(W[(kt * 32 + quad * 8 + j) * DEMB + nt * 16 + col]);

    float bv[4];
    #pragma unroll
    for (int nt = 0; nt < 4; nt++) bv[nt] = bias[nt * 16 + col];

    int row = base + col; if (row >= N) row = N - 1;
    short8 Af0 = *(const short8*)(G + (size_t)row * DEMB + quad * 8);
    short8 Af1 = *(const short8*)(G + (size_t)row * DEMB + 32 + quad * 8);

    f32x4 acc[4];
    #pragma unroll
    for (int nt = 0; nt < 4; nt++) {
        f32x4 z = {0.0f, 0.0f, 0.0f, 0.0f};
        z = __builtin_amdgcn_mfma_f32_16x16x32_bf16(Af0, Bf[nt][0], z, 0, 0, 0);
        z = __builtin_amdgcn_mfma_f32_16x16x32_bf16(Af1, Bf[nt][1], z, 0, 0, 0);
        acc[nt] = z;
    }

    #pragma unroll
    for (int reg = 0; reg < 4; reg++) {
        int node = base + quad * 4 + reg;
        if (node >= N) continue;
        float d = dis[node];
        float os = scaleOut ? d : 1.0f;
        #pragma unroll
        for (int nt = 0; nt < 4; nt++) {
            float y = fmaxf(acc[nt][reg] + bv[nt], 0.0f) * os;
            int u = __builtin_amdgcn_cvt_pk_fp8_f32(y, y, 0, false);
            hout8[(size_t)node * DEMB + nt * 16 + col] = (unsigned char)(u & 0xff);
        }
    }
}

// ---------------- decoder + softmax + residual ----------------

__global__ __launch_bounds__(256, 4) void decoder_kernel(
    const unsigned char* __restrict__ h8, const float* __restrict__ x,
    const float* __restrict__ dw1, const float* __restrict__ db1,
    const float* __restrict__ dw2, const float* __restrict__ db2,
    float* __restrict__ out, int N) {
    int lane = threadIdx.x & 63;
    int wid = __builtin_amdgcn_readfirstlane((blockIdx.x * blockDim.x + threadIdx.x) >> 6);
    int n0 = wid * 4;
    if (n0 >= N) return;

    float w1col[DEMB];
    #pragma unroll
    for (int k = 0; k < DEMB; k++) w1col[k] = dw1[k * DEMB + lane];
    float db1v = db1[lane];
    float w20 = dw2[lane * 2], w21 = dw2[lane * 2 + 1];
    float db20 = db2[0], db21 = db2[1];

    float xv = 0.0f;
    if (lane < 8 && n0 * 2 + lane < 2 * N) xv = x[n0 * 2 + lane];

    float myout = 0.0f;
    #pragma unroll
    for (int m = 0; m < 4; m++) {
        int node = n0 + m;
        if (node >= N) continue;
        float hv = __builtin_amdgcn_cvt_f32_fp8((int)h8[(size_t)node * 64 + lane], 0);
        float y = db1v;
        #pragma unroll
        for (int k = 0; k < DEMB; k++)
            y = fmaf(rdlane(hv, k), w1col[k], y);
        float d1 = fmaxf(y, 0.0f);
        float p0 = d1 * w20, p1 = d1 * w21;
        #pragma unroll
        for (int off = 32; off > 0; off >>= 1) {
            p0 += __shfl_xor(p0, off);
            p1 += __shfl_xor(p1, off);
        }
        float o0 = p0 + db20, o1 = p1 + db21;
        float mm = fmaxf(o0, o1);
        float e0 = __expf(o0 - mm), e1 = __expf(o1 - mm);
        float inv = 1.0f / (e0 + e1);
        float r0 = e0 * inv + 2.0f * rdlane(xv, 2 * m);   // wc = [2, 0]
        float r1 = e1 * inv;
        if (lane == 2 * m) myout = r0;
        if (lane == 2 * m + 1) myout = r1;
    }
    if (lane < 8 && n0 * 2 + lane < 2 * N)
        out[n0 * 2 + lane] = myout;
}

// ---------------- launch ----------------

extern "C" void kernel_launch(void* const* d_in, const int* in_sizes, int n_in,
                              void* d_out, int out_size, void* d_ws, size_t ws_size,
                              hipStream_t stream) {
    const float* x      = (const float*)d_in[0];
    const int*   ei     = (const int*)d_in[1];
    const float* ew     = (const float*)d_in[2];
    const float* enc_w1 = (const float*)d_in[3];
    const float* enc_b1 = (const float*)d_in[4];
    const float* enc_w2 = (const float*)d_in[5];
    const float* enc_b2 = (const float*)d_in[6];
    const float* gcn_w  = (const float*)d_in[7];
    const float* gcn_b  = (const float*)d_in[8];
    const float* dec_w1 = (const float*)d_in[9];
    const float* dec_b1 = (const float*)d_in[10];
    const float* dec_w2 = (const float*)d_in[11];
    const float* dec_b2 = (const float*)d_in[12];
    float* out = (float*)d_out;

    const int N = in_sizes[0] / 2;
    const int E = in_sizes[2];
    const int L = in_sizes[7] / (DEMB * DEMB);
    const int NBKT = (N + NPBKT - 1) / NPBKT;
    const int NWG = (E + CHUNK - 1) / CHUNK;

    size_t padcap = (size_t)E + (size_t)NWG * NBKT * 7 + 64;          // cells
    size_t csrcap = padcap + (size_t)NBKT * NPBKT * 7;                // + row pads

    // workspace layout (256B aligned); h rows 64 B fp8; G (bf16) aliases cells
    char* ws = (char*)d_ws;
    size_t o = 0;
    auto alignup = [](size_t v) { return (v + 255) & ~(size_t)255; };
    unsigned int* hA = (unsigned int*)(ws + o); o = alignup(o + (size_t)N * DEMB);
    unsigned int* hB = (unsigned int*)(ws + o); o = alignup(o + (size_t)N * DEMB);
    float* dis     = (float*)(ws + o); o = alignup(o + (size_t)N * 4);
    int2*  rowse   = (int2*)(ws + o);  o = alignup(o + (size_t)N * 8);
    int*   histM   = (int*)(ws + o);   o = alignup(o + (size_t)NWG * NBKT * 4);
    int*   bktcnt  = (int*)(ws + o);   o = alignup(o + (size_t)MAXBKT * 4);
    int*   bktbase = (int*)(ws + o);   o = alignup(o + (size_t)(MAXBKT + 1) * 4);
    size_t cells_bytes = padcap * 8, g_bytes = (size_t)N * 128;
    size_t un = cells_bytes > g_bytes ? cells_bytes : g_bytes;
    int2*  cells   = (int2*)(ws + o);
    unsigned int* Gbuf = (unsigned int*)(ws + o); o = alignup(o + un);
    int2*  csr     = (int2*)(ws + o);  o = alignup(o + csrcap * 8);

    const int TB = 256;
    dim3 blk(TB);
    dim3 gWave2((N * 32 + TB - 1) / TB);          // wave per 2 nodes
    dim3 gWave4((N * 16 + TB - 1) / TB);          // wave per 4 nodes
    int tiles = (N + 15) / 16;
    dim3 gTile((tiles + 3) / 4);                  // 4 waves (tiles) per block

    histA_kernel<<<NWG, blk, 0, stream>>>(ei, histM, E, NBKT);
    scanM_kernel<<<NBKT, blk, 0, stream>>>(histM, bktcnt, NWG, NBKT);
    scanB_kernel<<<1, 512, 0, stream>>>(bktcnt, bktbase, NBKT);
    binA_kernel<<<NWG, blk, 0, stream>>>(ei, ew, histM, bktbase, cells, E, NBKT);
    bucketB_kernel<<<NBKT, blk, 0, stream>>>(cells, bktbase, csr, rowse, dis, N);

    encoder_kernel<<<gWave4, blk, 0, stream>>>(x, dis, enc_w1, enc_b1, enc_w2, enc_b2, hA, N);

    unsigned int* hin = hA;
    unsigned int* hout = hB;
    for (int l = 0; l < L; l++) {
        agg_kernel<<<gWave2, blk, 0, stream>>>((const uint4*)hin, csr, rowse, dis,
                                               (uint4*)Gbuf, N);
        transform_kernel<<<gTile, blk, 0, stream>>>((const unsigned short*)Gbuf,
                                                    gcn_w + (size_t)l * DEMB * DEMB,
                                                    gcn_b + (size_t)l * DEMB, dis,
                                                    (unsigned char*)hout, N,
                                                    (l < L - 1) ? 1 : 0);
        unsigned int* t = hin; hin = hout; hout = t;
    }

    decoder_kernel<<<gWave4, blk, 0, stream>>>((const unsigned char*)hin, x,
                                               dec_w1, dec_b1, dec_w2, dec_b2, out, N);
}